// Round 9
// baseline (641.067 us; speedup 1.0000x reference)
//
#include <hip/hip_runtime.h>
#include <hip/hip_bf16.h>

#define T_STEPS 2048
#define BATCH 16
#define DIM 1024
#define EPSV 1e-6f
#define INVD (1.0f / 1024.0f)
#define SLOTF (BATCH * DIM)      // floats per [B][D] slot
#define SLOT4C (BATCH * DIM / 4) // float4 per slot

typedef short short8 __attribute__((ext_vector_type(8)));
typedef float f32x4 __attribute__((ext_vector_type(4)));

struct alignas(16) bf16x8pack { __hip_bfloat16 v[8]; };

__device__ __forceinline__ float dot4(const float4& a, const float4& c) {
  return fmaf(a.x, c.x, fmaf(a.y, c.y, fmaf(a.z, c.z, a.w * c.w)));
}
__device__ __forceinline__ float fast_rsq(float x) {
  float r;
  asm("v_rsq_f32 %0, %1" : "=v"(r) : "v"(x));
  return r;
}
__device__ __forceinline__ float lane63(float v) {
  return __int_as_float(__builtin_amdgcn_readlane(__float_as_int(v), 63));
}

// ---------------- fp32 -> bf16 convert (vectorized) ----------------
__global__ __launch_bounds__(256) void cvt_kernel(const float* __restrict__ src,
                                                  bf16x8pack* __restrict__ dst, int n8) {
  int i = blockIdx.x * blockDim.x + threadIdx.x;
  if (i >= n8) return;
  const float4* s4 = (const float4*)src + (size_t)i * 2;
  float4 a = s4[0];
  float4 b = s4[1];
  bf16x8pack p;
  p.v[0] = __float2bfloat16(a.x); p.v[1] = __float2bfloat16(a.y);
  p.v[2] = __float2bfloat16(a.z); p.v[3] = __float2bfloat16(a.w);
  p.v[4] = __float2bfloat16(b.x); p.v[5] = __float2bfloat16(b.y);
  p.v[6] = __float2bfloat16(b.z); p.v[7] = __float2bfloat16(b.w);
  dst[i] = p;
}

// ---------------- bf16 MFMA GEMM: out[m][e] = alpha*(sum_d X[m][d]*W[e][d] + b[e]) ----
__global__ __launch_bounds__(256) void gemm_kernel(
    const __hip_bfloat16* __restrict__ Xb,
    const __hip_bfloat16* __restrict__ Wb,
    const float* __restrict__ bias,
    const float* __restrict__ log_alpha_p,
    float* __restrict__ hreg) {
  __shared__ __hip_bfloat16 As[128 * 32];
  __shared__ __hip_bfloat16 Bs[128 * 32];
  const int tid = threadIdx.x;
  const int wave = tid >> 6, lane = tid & 63;
  const int m0 = blockIdx.y * 128;
  const int e0 = blockIdx.x * 128;
  const int wm = (wave >> 1) * 64;
  const int wn = (wave & 1) * 64;
  const int l15 = lane & 15, l4 = lane >> 4;

  f32x4 acc[4][4] = {};

  const int srow = wave * 16 + (lane >> 2);
  const int sch = (lane & 3) * 8;

  for (int kt = 0; kt < DIM; kt += 32) {
    __syncthreads();
#pragma unroll
    for (int i = 0; i < 2; ++i) {
      const __hip_bfloat16* ga = Xb + (size_t)(m0 + i * 64 + srow) * DIM + kt + sch;
      const __hip_bfloat16* gb = Wb + (size_t)(e0 + i * 64 + srow) * DIM + kt + sch;
      __builtin_amdgcn_global_load_lds(
          (const __attribute__((address_space(1))) void*)ga,
          (__attribute__((address_space(3))) void*)((char*)As + (i * 64 + wave * 16) * 64),
          16, 0, 0);
      __builtin_amdgcn_global_load_lds(
          (const __attribute__((address_space(1))) void*)gb,
          (__attribute__((address_space(3))) void*)((char*)Bs + (i * 64 + wave * 16) * 64),
          16, 0, 0);
    }
    __syncthreads();
    short8 a[4], b[4];
#pragma unroll
    for (int f = 0; f < 4; ++f)
      a[f] = *(const short8*)((const char*)As + ((wm + f * 16 + l15) * 32 + l4 * 8) * 2);
#pragma unroll
    for (int g = 0; g < 4; ++g)
      b[g] = *(const short8*)((const char*)Bs + ((wn + g * 16 + l15) * 32 + l4 * 8) * 2);
#pragma unroll
    for (int f = 0; f < 4; ++f)
#pragma unroll
      for (int g = 0; g < 4; ++g)
        acc[f][g] = __builtin_amdgcn_mfma_f32_16x16x32_bf16(a[f], b[g], acc[f][g], 0, 0, 0);
  }
  const float alpha = __expf(log_alpha_p[0]);
#pragma unroll
  for (int g = 0; g < 4; ++g) {
    const int e = e0 + wn + g * 16 + l15;
    const float bv = bias[e];
#pragma unroll
    for (int f = 0; f < 4; ++f) {
#pragma unroll
      for (int r = 0; r < 4; ++r) {
        const int m = m0 + wm + f * 16 + l4 * 4 + r;
        hreg[(size_t)(m + BATCH) * DIM + e] = alpha * (acc[f][g][r] + bv);
      }
    }
  }
}

// ---------------- DPP wave-sum helper (total lands in lane 63) ----------------
__device__ __forceinline__ float dpp_sum_reg(float x) {
  float acc = x;
#define DPP_ADD(ctrl)                                                              \
  {                                                                                \
    int t_ = __builtin_amdgcn_update_dpp(0, __float_as_int(acc), (ctrl), 0xf, 0xf, \
                                         true);                                    \
    acc += __int_as_float(t_);                                                     \
  }
  DPP_ADD(0x111); DPP_ADD(0x112); DPP_ADD(0x114); DPP_ADD(0x118);
  DPP_ADD(0x142); DPP_ADD(0x143);
#undef DPP_ADD
  return acc;
}

// ---- precompute: scal4[t] = (e, 2d, 2d2, 2d3)   (d_k = W_{t-k}.W_t) ----
__global__ __launch_bounds__(64) void dots_kernel(const float* __restrict__ hreg,
                                                  float4* __restrict__ scal4) {
  const int t = blockIdx.x >> 4;
  const int b = blockIdx.x & 15;
  const int lane = threadIdx.x;
  const float4* w  = (const float4*)(hreg + (size_t)(t + 1) * SLOTF + b * DIM);
  const float4* m1 = (const float4*)(hreg + (size_t)(t    ) * SLOTF + b * DIM);
  const float4* m2 = (const float4*)(hreg + (size_t)(t - 1) * SLOTF + b * DIM);
  const float4* m3 = (const float4*)(hreg + (size_t)(t - 2) * SLOTF + b * DIM);
  float e = 0.f, d = 0.f, d2 = 0.f, d3 = 0.f;
#pragma unroll
  for (int j = 0; j < 4; ++j) {
    float4 a = w[lane + 64 * j];
    e = fmaf(a.x, a.x, fmaf(a.y, a.y, fmaf(a.z, a.z, fmaf(a.w, a.w, e))));
    if (t >= 1) { float4 p = m1[lane + 64 * j];
      d = fmaf(p.x, a.x, fmaf(p.y, a.y, fmaf(p.z, a.z, fmaf(p.w, a.w, d)))); }
    if (t >= 2) { float4 p = m2[lane + 64 * j];
      d2 = fmaf(p.x, a.x, fmaf(p.y, a.y, fmaf(p.z, a.z, fmaf(p.w, a.w, d2)))); }
    if (t >= 3) { float4 p = m3[lane + 64 * j];
      d3 = fmaf(p.x, a.x, fmaf(p.y, a.y, fmaf(p.z, a.z, fmaf(p.w, a.w, d3)))); }
  }
  e = dpp_sum_reg(e);
  d = dpp_sum_reg(d);
  d2 = dpp_sum_reg(d2);
  d3 = dpp_sum_reg(d3);
  if (lane == 63) scal4[b * T_STEPS + t] = make_float4(e, d + d, d2 + d2, d3 + d3);
}

// ---------------- sequential scan: ONE WAVE PER ROW (no barriers, no LDS) --------
// Lane owns 16 floats (4 float4, stride-64 coalesced). Depth-3 scalar recurrence:
//   BB_i = 2(s_i.W_i) = 2d + rm1*(2d2 + rm2*(2d3 + 2G_i)),  G_i = h_{i-3}.W_i
//   n_{i+1} = rinv*(rinv*n + BB) + e ;  h_i = rinv*s_i ;  s_{i+1} = h_i + W_i
// G-dot is wave-local: DPP partial at step i-1..i-3, readlane next step, used at
// step i. W ring-8 in registers (8-step prefetch), scal 4-ring from global
// (4-step slack, L3-resident). hv alternates parity regs (2-step store slack).
// RING INVARIANT (r9 fix): slot k is refilled with W_{i+8} right after step i
// (i == k mod 8) consumes it; w[0]'s initial W_0 is consumed by the s_1 init, so
// w[0] MUST be refilled to W_8 immediately after (this was round 8's bug).
__global__ __launch_bounds__(64, 1) void scan_kernel(
    const float* __restrict__ h0,
    const float4* __restrict__ scal4,
    float* __restrict__ hreg) {
  const int b = blockIdx.x;
  const int lane = threadIdx.x;
  float4* h4 = (float4*)hreg;
  const int base = b * 256 + lane;
  const float4* scg = scal4 + b * T_STEPS;

  // W ring-8: w[k] = W_k (hreg slot k+1)
  float4 w[8][4];
#pragma unroll
  for (int k = 0; k < 8; ++k)
#pragma unroll
    for (int j = 0; j < 4; ++j)
      w[k][j] = h4[(size_t)SLOT4C * (k + 1) + base + 64 * j];

  float4 scr[4];
  scr[1] = scg[1]; scr[2] = scg[2]; scr[3] = scg[3]; scr[0] = scg[4];

  float4 s[4], hvE[4], hvO[4];
  float4 h0v[4];
#pragma unroll
  for (int j = 0; j < 4; ++j) h0v[j] = ((const float4*)h0)[base + 64 * j];
#pragma unroll
  for (int j = 0; j < 4; ++j) h4[base + 64 * j] = h0v[j];  // slot 0 = h_0
#pragma unroll
  for (int j = 0; j < 4; ++j) {
    s[j].x = h0v[j].x + w[0][j].x; s[j].y = h0v[j].y + w[0][j].y;
    s[j].z = h0v[j].z + w[0][j].z; s[j].w = h0v[j].w + w[0][j].w;
  }
  // r9 FIX: w[0]'s W_0 is now consumed -> refill with W_8 (hreg slot 9) so the
  // ring invariant holds at step 8 (s-update) and step 5 (G-dot uses W_8).
#pragma unroll
  for (int j = 0; j < 4; ++j) w[0][j] = h4[(size_t)SLOT4C * 9 + base + 64 * j];

  // startup wave-local dots: n1=||s1||^2, b1=s1.W1, c2=s1.W2, c3=s1.W3
#define WDOT(RES, AV, BV)                                                          \
  {                                                                                \
    float p0_ = dot4(AV[0], BV[0]), p1_ = dot4(AV[1], BV[1]);                      \
    float p2_ = dot4(AV[2], BV[2]), p3_ = dot4(AV[3], BV[3]);                      \
    RES = lane63(dpp_sum_reg((p0_ + p1_) + (p2_ + p3_)));                          \
  }
  float n, b1c, c2, c3;
  WDOT(n, s, s)
  WDOT(b1c, s, w[1])
  WDOT(c2, s, w[2])
  WDOT(c3, s, w[3])

  float rm1, rm2, gE = 0.f, gO = 0.f, ppA, ppB;

  // ---- step 1 (odd): BB = 2*b1c
  {
    const float BB = b1c + b1c;
    const float rinv = fast_rsq(fmaf(n, INVD, EPSV));
    n = fmaf(rinv, fmaf(rinv, n, BB), scr[1].x);
#pragma unroll
    for (int j = 0; j < 4; ++j) {
      hvO[j].x = rinv * s[j].x; hvO[j].y = rinv * s[j].y;
      hvO[j].z = rinv * s[j].z; hvO[j].w = rinv * s[j].w;
    }
#pragma unroll
    for (int j = 0; j < 4; ++j) h4[(size_t)SLOT4C * 1 + base + 64 * j] = hvO[j];
#pragma unroll
    for (int j = 0; j < 4; ++j) {
      s[j].x = hvO[j].x + w[1][j].x; s[j].y = hvO[j].y + w[1][j].y;
      s[j].z = hvO[j].z + w[1][j].z; s[j].w = hvO[j].w + w[1][j].w;
    }
    float p0 = dot4(hvO[0], w[4][0]), p1 = dot4(hvO[1], w[4][1]);
    float p2 = dot4(hvO[2], w[4][2]), p3 = dot4(hvO[3], w[4][3]);
    ppB = dpp_sum_reg((p0 + p1) + (p2 + p3));  // G_4 partial
#pragma unroll
    for (int j = 0; j < 4; ++j) w[1][j] = h4[(size_t)SLOT4C * 10 + base + 64 * j];  // W_9
    scr[1] = scg[5];
    rm1 = rinv;
  }
  // ---- step 2 (even): BB = 2d_2 + rm1*2c2 ; gE = 2*G_4
  {
    const float BB = fmaf(rm1, c2 + c2, scr[2].y);
    const float rinv = fast_rsq(fmaf(n, INVD, EPSV));
    n = fmaf(rinv, fmaf(rinv, n, BB), scr[2].x);
    { const float sg = lane63(ppB); gE = sg + sg; }
#pragma unroll
    for (int j = 0; j < 4; ++j) {
      hvE[j].x = rinv * s[j].x; hvE[j].y = rinv * s[j].y;
      hvE[j].z = rinv * s[j].z; hvE[j].w = rinv * s[j].w;
    }
#pragma unroll
    for (int j = 0; j < 4; ++j) h4[(size_t)SLOT4C * 2 + base + 64 * j] = hvE[j];
#pragma unroll
    for (int j = 0; j < 4; ++j) {
      s[j].x = hvE[j].x + w[2][j].x; s[j].y = hvE[j].y + w[2][j].y;
      s[j].z = hvE[j].z + w[2][j].z; s[j].w = hvE[j].w + w[2][j].w;
    }
    float p0 = dot4(hvE[0], w[5][0]), p1 = dot4(hvE[1], w[5][1]);
    float p2 = dot4(hvE[2], w[5][2]), p3 = dot4(hvE[3], w[5][3]);
    ppA = dpp_sum_reg((p0 + p1) + (p2 + p3));  // G_5 partial
#pragma unroll
    for (int j = 0; j < 4; ++j) w[2][j] = h4[(size_t)SLOT4C * 11 + base + 64 * j];  // W_10
    scr[2] = scg[6];
    rm2 = rm1; rm1 = rinv;
  }
  // ---- step 3 (odd): BB = 2d_3 + rm1*(2d2_3 + rm2*2c3) ; gO = 2*G_5
  {
    const float BB = fmaf(rm1, fmaf(rm2, c3 + c3, scr[3].z), scr[3].y);
    const float rinv = fast_rsq(fmaf(n, INVD, EPSV));
    n = fmaf(rinv, fmaf(rinv, n, BB), scr[3].x);
    { const float sg = lane63(ppA); gO = sg + sg; }
#pragma unroll
    for (int j = 0; j < 4; ++j) {
      hvO[j].x = rinv * s[j].x; hvO[j].y = rinv * s[j].y;
      hvO[j].z = rinv * s[j].z; hvO[j].w = rinv * s[j].w;
    }
#pragma unroll
    for (int j = 0; j < 4; ++j) h4[(size_t)SLOT4C * 3 + base + 64 * j] = hvO[j];
#pragma unroll
    for (int j = 0; j < 4; ++j) {
      s[j].x = hvO[j].x + w[3][j].x; s[j].y = hvO[j].y + w[3][j].y;
      s[j].z = hvO[j].z + w[3][j].z; s[j].w = hvO[j].w + w[3][j].w;
    }
    float p0 = dot4(hvO[0], w[6][0]), p1 = dot4(hvO[1], w[6][1]);
    float p2 = dot4(hvO[2], w[6][2]), p3 = dot4(hvO[3], w[6][3]);
    ppB = dpp_sum_reg((p0 + p1) + (p2 + p3));  // G_6 partial
#pragma unroll
    for (int j = 0; j < 4; ++j) w[3][j] = h4[(size_t)SLOT4C * 12 + base + 64 * j];  // W_11
    scr[3] = scg[7];
    rm2 = rm1; rm1 = rinv;
  }

// Steady step: G read from GREG (set 2 steps ago), GREG <- 2*lane63(PPO).
#define STEP(I_, WS, W3S, SCS, HV, PPN, PPO, GREG)                                 \
  {                                                                                \
    const int i_ = (I_);                                                           \
    const float4 sc = scr[SCS];                                                    \
    const float BB = fmaf(rm1, fmaf(rm2, sc.w + GREG, sc.z), sc.y);                \
    { const float sg_ = lane63(PPO); GREG = sg_ + sg_; }                           \
    const float rinv = fast_rsq(fmaf(n, INVD, EPSV));                              \
    n = fmaf(rinv, fmaf(rinv, n, BB), sc.x);                                       \
    _Pragma("unroll")                                                              \
    for (int j = 0; j < 4; ++j) {                                                  \
      HV[j].x = rinv * s[j].x; HV[j].y = rinv * s[j].y;                            \
      HV[j].z = rinv * s[j].z; HV[j].w = rinv * s[j].w;                            \
    }                                                                              \
    _Pragma("unroll")                                                              \
    for (int j = 0; j < 4; ++j)                                                    \
      h4[(size_t)SLOT4C * i_ + base + 64 * j] = HV[j];                             \
    _Pragma("unroll")                                                              \
    for (int j = 0; j < 4; ++j) {                                                  \
      s[j].x = HV[j].x + w[WS][j].x; s[j].y = HV[j].y + w[WS][j].y;                \
      s[j].z = HV[j].z + w[WS][j].z; s[j].w = HV[j].w + w[WS][j].w;                \
    }                                                                              \
    {                                                                              \
      float p0_ = dot4(HV[0], w[W3S][0]), p1_ = dot4(HV[1], w[W3S][1]);            \
      float p2_ = dot4(HV[2], w[W3S][2]), p3_ = dot4(HV[3], w[W3S][3]);            \
      PPN = dpp_sum_reg((p0_ + p1_) + (p2_ + p3_));                                \
    }                                                                              \
    const int ipf_ = (i_ + 8 < T_STEPS) ? (i_ + 8) : (T_STEPS - 1);                \
    _Pragma("unroll")                                                              \
    for (int j = 0; j < 4; ++j)                                                    \
      w[WS][j] = h4[(size_t)SLOT4C * (ipf_ + 1) + base + 64 * j];                  \
    const int isc_ = (i_ + 4 < T_STEPS) ? (i_ + 4) : (T_STEPS - 1);                \
    scr[SCS] = scg[isc_];                                                          \
    rm2 = rm1; rm1 = rinv;                                                         \
  }

  // main loop: i = 4..2043 (255 chunks of 8, ii ≡ 4 mod 8)
  for (int ii = 4; ii < 2044; ii += 8) {
    STEP(ii + 0, 4, 7, 0, hvE, ppA, ppB, gE)
    STEP(ii + 1, 5, 0, 1, hvO, ppB, ppA, gO)
    STEP(ii + 2, 6, 1, 2, hvE, ppA, ppB, gE)
    STEP(ii + 3, 7, 2, 3, hvO, ppB, ppA, gO)
    STEP(ii + 4, 0, 3, 0, hvE, ppA, ppB, gE)
    STEP(ii + 5, 1, 4, 1, hvO, ppB, ppA, gO)
    STEP(ii + 6, 2, 5, 2, hvE, ppA, ppB, gE)
    STEP(ii + 7, 3, 6, 3, hvO, ppB, ppA, gO)
  }
  // tail: i = 2044..2047
  STEP(2044, 4, 7, 0, hvE, ppA, ppB, gE)
  STEP(2045, 5, 0, 1, hvO, ppB, ppA, gO)
  STEP(2046, 6, 1, 2, hvE, ppA, ppB, gE)
  STEP(2047, 7, 2, 3, hvO, ppB, ppA, gO)
#undef STEP
#undef WDOT

  // final: h_2048 = rinv * s -> slot 2048
  const float rinvT = fast_rsq(fmaf(n, INVD, EPSV));
#pragma unroll
  for (int j = 0; j < 4; ++j) {
    float4 o;
    o.x = rinvT * s[j].x; o.y = rinvT * s[j].y;
    o.z = rinvT * s[j].z; o.w = rinvT * s[j].w;
    h4[(size_t)SLOT4C * T_STEPS + base + 64 * j] = o;
  }
}

// ---------------- outs[t] = h_{t+1} * silu(h_{t+1}) ----------------
__global__ __launch_bounds__(256) void silu_kernel(const float4* __restrict__ hsrc,
                                                   float4* __restrict__ out4, int n4) {
  int i = blockIdx.x * blockDim.x + threadIdx.x;
  if (i >= n4) return;
  float4 h = hsrc[i];
  float4 o;
  o.x = h.x * h.x / (1.f + __expf(-h.x));
  o.y = h.y * h.y / (1.f + __expf(-h.y));
  o.z = h.z * h.z / (1.f + __expf(-h.z));
  o.w = h.w * h.w / (1.f + __expf(-h.w));
  out4[i] = o;
}

extern "C" void kernel_launch(void* const* d_in, const int* in_sizes, int n_in,
                              void* d_out, int out_size, void* d_ws, size_t ws_size,
                              hipStream_t stream) {
  (void)in_sizes; (void)n_in; (void)d_ws; (void)ws_size; (void)out_size;
  const float* x = (const float*)d_in[0];
  const float* h0 = (const float*)d_in[1];
  const float* W = (const float*)d_in[2];
  const float* bias = (const float*)d_in[3];
  const float* log_alpha = (const float*)d_in[4];

  float* out = (float*)d_out;                               // outs region [T][B][D]
  float* hreg = out + (size_t)T_STEPS * BATCH * DIM;        // h region [T+1][B][D]
  // staging overlays the outs region (consumed before scan/silu touch it)
  __hip_bfloat16* xb = (__hip_bfloat16*)d_out;
  __hip_bfloat16* wb = (__hip_bfloat16*)((char*)d_out + (size_t)T_STEPS * BATCH * DIM * 2);
  float4* scal4 = (float4*)(out + (size_t)26 * 1024 * 1024);  // 104 MB offset

  const int nx8 = T_STEPS * BATCH * DIM / 8;
  const int nw8 = DIM * DIM / 8;
  cvt_kernel<<<nx8 / 256, 256, 0, stream>>>(x, (bf16x8pack*)xb, nx8);
  cvt_kernel<<<nw8 / 256, 256, 0, stream>>>(W, (bf16x8pack*)wb, nw8);

  dim3 ggrid(DIM / 128, (T_STEPS * BATCH) / 128);
  gemm_kernel<<<ggrid, 256, 0, stream>>>(xb, wb, bias, log_alpha, hreg);

  dots_kernel<<<T_STEPS * BATCH, 64, 0, stream>>>(hreg, scal4);

  scan_kernel<<<BATCH, 64, 0, stream>>>(h0, scal4, hreg);

  const int n4 = T_STEPS * BATCH * DIM / 4;
  silu_kernel<<<n4 / 256, 256, 0, stream>>>((const float4*)(hreg + BATCH * DIM),
                                            (float4*)out, n4);
}